// Round 1
// baseline (374.674 us; speedup 1.0000x reference)
//
#include <hip/hip_runtime.h>

typedef unsigned short u16;
typedef __attribute__((ext_vector_type(8))) short bf16x8;
typedef __attribute__((ext_vector_type(4))) float f32x4;

// Problem: B=8, S=1024, D=1024, H=16, DK=64.
// d_in = {mask:int32, x:f32, wq:f32, wk:f32, wv:f32, wo:f32}. Output: float32.
// Compute path: f32 -> bf16, MFMA 16x16x32 bf16, fp32 accumulate.
// NOTE (R9): hipLaunchCooperativeKernel silently failed in this harness — do not use.

static __device__ __forceinline__ u16 f2bf(float f) {
    union { float f; unsigned u; } v; v.f = f;
    unsigned r = v.u + 0x7fffu + ((v.u >> 16) & 1u);
    return (u16)(r >> 16);
}

static __device__ __forceinline__ f32x4 mfma16(bf16x8 a, bf16x8 b, f32x4 c) {
    return __builtin_amdgcn_mfma_f32_16x16x32_bf16(a, b, c, 0, 0, 0);
}

// async global->LDS, 16 bytes per lane (global_load_lds_dwordx4)
static __device__ __forceinline__ void load_lds16(const u16* g, u16* l) {
    __builtin_amdgcn_global_load_lds((const __attribute__((address_space(1))) unsigned*)(const void*)g,
                                     (__attribute__((address_space(3))) unsigned*)(void*)l, 16, 0, 0);
}

// ---------------- fused prep: cvt_x | cvt_w | pack_mask | zero sums ----------------
// grid 57344: [0,8192) cvt_x, [8192,24576) cvt_w, [24576,57344) pack_mask
__global__ __launch_bounds__(256) void prep_kernel(const float* __restrict__ x,
                                                   const float* __restrict__ wq, const float* __restrict__ wk,
                                                   const float* __restrict__ wv, const float* __restrict__ wo,
                                                   const int* __restrict__ mask,
                                                   u16* __restrict__ xb, u16* __restrict__ wt,
                                                   u16* __restrict__ wot, uint2* __restrict__ mb,
                                                   float* __restrict__ sums) {
    int bid = blockIdx.x;
    if (bid == 0 && threadIdx.x < 16) sums[threadIdx.x] = 0.f;  // zero LN accumulators
    if (bid < 8192) {
        int i = (bid * 256 + threadIdx.x) * 4;  // 8388608 elems
        float4 v = *(const float4*)(x + i);
        ushort4 o;
        o.x = f2bf(v.x); o.y = f2bf(v.y); o.z = f2bf(v.z); o.w = f2bf(v.w);
        *(ushort4*)(xb + i) = o;
    } else if (bid < 24576) {
        int o = (bid - 8192) * 256 + threadIdx.x;  // 4194304 elems
        if (o < 3145728) {
            int z = o >> 20;
            int rem = o & 1048575;
            int n = rem >> 10;
            int d = rem & 1023;
            int h = n >> 6, kk = n & 63;
            const float* w = (z == 0) ? wq : (z == 1) ? wk : wv;
            wt[o] = f2bf(w[h * 65536 + d * 64 + kk]);
        } else {
            int oo = o - 3145728;
            int n = oo >> 10, d = oo & 1023;
            wot[oo] = f2bf(wo[d * 1024 + n]);
        }
    } else {
        long long wi = (long long)(bid - 24576) * 4 + (threadIdx.x >> 6);  // 131072 words
        int lane = threadIdx.x & 63;
        int v = mask[wi * 64 + lane];
        unsigned long long bal = __ballot(v != 0);
        if (lane == 0) {
            uint2 o; o.x = (unsigned)bal; o.y = (unsigned)(bal >> 32);
            mb[wi] = o;
        }
    }
}

// ---------------- fused QKV projection GEMM: 256x256 tile, 8-phase deep pipeline ----------------
// M=8192, N=3072, K=1024. grid 384 (32 m-tiles x 12 n-tiles, XCD-swizzled), block 512 (8 waves, 2Mx4N).
//
// LDS (128 KiB) = 8 slots x 16 KiB. Slot s = (kt&1)*4 + {0:A-khalf0, 1:A-khalf1, 2:B-khalf0, 3:B-khalf1}.
// Each slot = 256 rows x 32 k bf16, stored as 16 subtiles of [16 rows][32 k] (1024 B), with st_16x32
// swizzle: phys_byte = logical_byte ^ (((logical>>9)&1)<<5)  (== XOR 32B when row&8). Staged via
// pre-swizzled GLOBAL source + linear global_load_lds dest (both-sides-or-neither).
//
// Iteration i computes kt=2i (phases 1-4: ks0/niH0, ks0/niH1, ks1/niH0, ks1/niH1) and kt=2i+1
// (phases 5-8). Staging stream (1 K-half per phase, 5-6 phases ahead of first read):
//   p1:A1(2i+1) p2:B1(2i+1) p3:A0(2i+2) p4:B0(2i+2) p5:A1(2i+2) p6:B1(2i+2) p7:A0(2i+3) p8:B0(2i+3)
// Counted waits: vmcnt(4) at p4/p8 only ("everything older than the last 2 half-tiles has landed"),
// which exactly guarantees the next 4-phase window's 4 K-halves are resident. Never vmcnt(0) in the
// main loop. Slot WAR safety verified per-phase (each stage targets a slot last read >=1 barrier ago).
// Q pre-scaled by 1/sqrt(DK)=0.125 in the epilogue.
__global__ __launch_bounds__(512, 2) void qkv_gemm_kernel(const u16* __restrict__ xb, const u16* __restrict__ wt,
                                                          u16* __restrict__ qb, u16* __restrict__ kb,
                                                          u16* __restrict__ vtb) {
    __shared__ __align__(16) u16 L[8 * 8192];

    int t = threadIdx.x;
    int lane = t & 63, w = t >> 6;
    int wm = w & 1, wn = w >> 1;         // 2 M-waves x 4 N-waves; wave tile 128x64
    int l16 = lane & 15, quad = lane >> 4;

    // XCD-bijective block swizzle (384 % 8 == 0): consecutive ids within an XCD walk m fast.
    int id = blockIdx.x;
    int swz = (id & 7) * 48 + (id >> 3);
    int m0 = (swz & 31) * 256;
    int n0 = (swz >> 5) * 256;

    // Staging decode: thread t writes phys LDS bytes [c*8192 + t*16, +16). Un-swizzling gives
    // global row (within 256-row panel) and k start (within the 32-k half):
    int grow = (t >> 6) * 16 + ((t >> 2) & 15);        // + c*128
    int gk = ((t & 3) * 8) ^ ((t & 32) ? 16 : 0);      // pre-swizzled source k
    const u16* ga = xb + (m0 + grow) * 1024 + gk;
    const u16* gb = wt + (n0 + grow) * 1024 + gk;

    // Fragment read offsets (u16 units) incl. swizzle: row = 16*sub_r + l16, k = quad*8 (^16 if l16&8)
    int fsw = (l16 & 8) ? 16 : 0;
    int abase = (wm * 8) * 512 + l16 * 32 + ((quad * 8) ^ fsw);
    int bbase = (wn * 4) * 512 + l16 * 32 + ((quad * 8) ^ fsw);

    f32x4 acc[8][4];
#pragma unroll
    for (int i = 0; i < 8; ++i)
#pragma unroll
        for (int j = 0; j < 4; ++j) acc[i][j] = (f32x4){0.f, 0.f, 0.f, 0.f};
    bf16x8 af[8];

#define STAGE_A(kt, ks) { const u16* g_ = ga + (kt) * 64 + (ks) * 32;            \
        u16* d_ = &L[(((kt) & 1) * 4 + (ks)) * 8192];                            \
        load_lds16(g_, d_ + t * 8);                                              \
        load_lds16(g_ + 131072, d_ + 4096 + t * 8); }
#define STAGE_B(kt, ks) { const u16* g_ = gb + (kt) * 64 + (ks) * 32;            \
        u16* d_ = &L[(((kt) & 1) * 4 + 2 + (ks)) * 8192];                        \
        load_lds16(g_, d_ + t * 8);                                              \
        load_lds16(g_ + 131072, d_ + 4096 + t * 8); }
#define VM4 asm volatile("s_waitcnt vmcnt(4)" ::: "memory");
#define VM0 asm volatile("s_waitcnt vmcnt(0)" ::: "memory");

#define PHASE(kt, ks, niH, STG, WT) {                                            \
        const u16* SA_ = &L[(((kt) & 1) * 4 + (ks)) * 8192];                     \
        const u16* SB_ = &L[(((kt) & 1) * 4 + 2 + (ks)) * 8192];                 \
        if ((niH) == 0) {                                                        \
            _Pragma("unroll")                                                    \
            for (int mi = 0; mi < 8; ++mi)                                       \
                af[mi] = *(const bf16x8*)&SA_[abase + mi * 512];                  \
        }                                                                        \
        bf16x8 b0_ = *(const bf16x8*)&SB_[bbase + ((niH) * 2 + 0) * 512];        \
        bf16x8 b1_ = *(const bf16x8*)&SB_[bbase + ((niH) * 2 + 1) * 512];        \
        STG                                                                      \
        __builtin_amdgcn_s_barrier();                                            \
        asm volatile("s_waitcnt lgkmcnt(0)" ::: "memory");                       \
        __builtin_amdgcn_sched_barrier(0);                                       \
        __builtin_amdgcn_s_setprio(1);                                           \
        _Pragma("unroll")                                                        \
        for (int mi = 0; mi < 8; ++mi) {                                         \
            acc[mi][(niH) * 2 + 0] = mfma16(af[mi], b0_, acc[mi][(niH) * 2 + 0]);\
            acc[mi][(niH) * 2 + 1] = mfma16(af[mi], b1_, acc[mi][(niH) * 2 + 1]);\
        }                                                                        \
        __builtin_amdgcn_s_setprio(0);                                           \
        WT                                                                       \
        __builtin_amdgcn_s_barrier(); }

    // prologue: kt0 fully + kt1 K-half0; vmcnt(4) leaves only the last 2 half-tiles in flight
    STAGE_A(0, 0) STAGE_B(0, 0) STAGE_A(0, 1) STAGE_B(0, 1) STAGE_A(1, 0) STAGE_B(1, 0)
    VM4
    __builtin_amdgcn_s_barrier();

    for (int i = 0; i < 7; ++i) {
        int k0 = 2 * i, k1 = 2 * i + 1, k2 = 2 * i + 2, k3 = 2 * i + 3;
        PHASE(k0, 0, 0, STAGE_A(k1, 1), )       // p1
        PHASE(k0, 0, 1, STAGE_B(k1, 1), )       // p2
        PHASE(k0, 1, 0, STAGE_A(k2, 0), )       // p3
        PHASE(k0, 1, 1, STAGE_B(k2, 0), VM4)    // p4
        PHASE(k1, 0, 0, STAGE_A(k2, 1), )       // p5
        PHASE(k1, 0, 1, STAGE_B(k2, 1), )       // p6
        PHASE(k1, 1, 0, STAGE_A(k3, 0), )       // p7
        PHASE(k1, 1, 1, STAGE_B(k3, 0), VM4)    // p8
    }
    // tail: kt14, kt15 (A0/B0(15) staged in iter 6 p7/p8); drain once at p4
    PHASE(14, 0, 0, STAGE_A(15, 1), )
    PHASE(14, 0, 1, STAGE_B(15, 1), )
    PHASE(14, 1, 0, , )
    PHASE(14, 1, 1, , VM0)
    PHASE(15, 0, 0, , )
    PHASE(15, 0, 1, , )
    PHASE(15, 1, 0, , )
    PHASE(15, 1, 1, , )

#undef PHASE
#undef STAGE_A
#undef STAGE_B
#undef VM4
#undef VM0

    // epilogue: scatter to per-head Q/K/V layouts (z uniform per block since 256 | 1024)
    int z = n0 >> 10;
    float qscale = (z == 0) ? 0.125f : 1.0f;
#pragma unroll
    for (int mi = 0; mi < 8; ++mi) {
#pragma unroll
        for (int r = 0; r < 4; ++r) {
            int m = m0 + wm * 128 + mi * 16 + quad * 4 + r;
            int b_ = m >> 10, s = m & 1023;
#pragma unroll
            for (int ni = 0; ni < 4; ++ni) {
                int ng = n0 + wn * 64 + ni * 16 + l16;
                int nl = ng & 1023;
                int h = nl >> 6, kk = nl & 63;
                u16 val = f2bf(acc[mi][ni][r] * qscale);
                if (z == 0)      qb[((b_ * 16 + h) * 1024 + s) * 64 + kk] = val;
                else if (z == 1) kb[((b_ * 16 + h) * 1024 + s) * 64 + kk] = val;
                else             vtb[((b_ * 16 + h) * 64 + kk) * 1024 + s] = val;
            }
        }
    }
}

// ---------------- flash attention: LDS-staged K/V + bitmask ----------------
// grid (S/64, H, B), block 256 = 4 waves; wave: 16 queries, 64-key tiles.
__global__ __launch_bounds__(256) void attn_kernel(const u16* __restrict__ qb, const u16* __restrict__ kb,
                                                   const u16* __restrict__ vtb, const uint2* __restrict__ mb,
                                                   u16* __restrict__ ctx) {
    __shared__ __align__(16) u16 Ks[64 * 64];
    __shared__ __align__(16) u16 Vs[64 * 64];
    __shared__ __align__(16) u16 P[4][16][72];  // rows padded: 36 dw stride -> <=2-way (free)

    int t = threadIdx.x;
    int w = t >> 6, lane = t & 63;
    int l16 = lane & 15, quad = lane >> 4;
    int h = blockIdx.y, b = blockIdx.z;
    int q0 = blockIdx.x * 64 + w * 16;

    const u16* Q = qb + (b * 16 + h) * 65536;
    const u16* K = kb + (b * 16 + h) * 65536;
    const u16* Vt = vtb + (b * 16 + h) * 65536;
    const uint2* MB = mb + (b * 1024 + q0) * 16;

    int srow = t >> 3;
    int skp = ((t & 7) ^ (srow & 7)) * 8;
    const u16* gk0 = K + srow * 64 + skp;          // + (k0+c*32)*64
    const u16* gv0 = Vt + srow * 1024 + skp;       // + c*32*1024 + k0

    bf16x8 qf0 = *(const bf16x8*)(Q + (q0 + l16) * 64 + quad * 8);
    bf16x8 qf1 = *(const bf16x8*)(Q + (q0 + l16) * 64 + 32 + quad * 8);

    f32x4 O[4];
#pragma unroll
    for (int j = 0; j < 4; ++j) O[j] = (f32x4){0.f, 0.f, 0.f, 0.f};
    float lsum[4] = {0.f, 0.f, 0.f, 0.f};

    int sw = l16 & 7;

    for (int kt0 = 0; kt0 < 16; ++kt0) {
        int k0 = kt0 * 64;

        // hoist mask-word loads: issue before the barriers, consume after staging
        uint2 mw[4];
#pragma unroll
        for (int r = 0; r < 4; ++r)
            mw[r] = MB[(quad * 4 + r) * 16 + kt0];

        __syncthreads();
#pragma unroll
        for (int c = 0; c < 2; ++c) {
            load_lds16(gk0 + (k0 + c * 32) * 64, &Ks[c * 2048 + t * 8]);
            load_lds16(gv0 + c * 32 * 1024 + k0, &Vs[c * 2048 + t * 8]);
        }
        __syncthreads();

        f32x4 s[4];
#pragma unroll
        for (int kt = 0; kt < 4; ++kt) {
            int row = kt * 16 + l16;
            bf16x8 klo = *(const bf16x8*)&Ks[row * 64 + ((quad ^ sw) * 8)];
            bf16x8 khi = *(const bf16x8*)&Ks[row * 64 + (((4 + quad) ^ sw) * 8)];
            f32x4 z = {0.f, 0.f, 0.f, 0.f};
            z = mfma16(qf0, klo, z);
            z = mfma16(qf1, khi, z);
            s[kt] = z;
        }

#pragma unroll
        for (int r = 0; r < 4; ++r) {
            int qrow = quad * 4 + r;
#pragma unroll
            for (int kt = 0; kt < 4; ++kt) {
                unsigned wsel = (kt < 2) ? mw[r].x : mw[r].y;
                unsigned bit = (wsel >> ((kt & 1) * 16 + l16)) & 1u;
                float e = bit ? __expf(s[kt][r]) : 0.f;
                lsum[r] += e;
                P[w][qrow][kt * 16 + l16] = f2bf(e);
            }
        }

        // P: C-layout -> A-layout via same-wave LDS round trip (in-order DS pipe, no barrier)
        bf16x8 pf0 = *(const bf16x8*)&P[w][l16][quad * 8];
        bf16x8 pf1 = *(const bf16x8*)&P[w][l16][32 + quad * 8];

#pragma unroll
        for (int j = 0; j < 4; ++j) {
            int row = j * 16 + l16;
            bf16x8 vlo = *(const bf16x8*)&Vs[row * 64 + ((quad ^ sw) * 8)];
            bf16x8 vhi = *(const bf16x8*)&Vs[row * 64 + (((4 + quad) ^ sw) * 8)];
            O[j] = mfma16(pf0, vlo, O[j]);
            O[j] = mfma16(pf1, vhi, O[j]);
        }
    }

#pragma unroll
    for (int r = 0; r < 4; ++r) {
        float s = lsum[r];
        s += __shfl_xor(s, 1);
        s += __shfl_xor(s, 2);
        s += __shfl_xor(s, 4);
        s += __shfl_xor(s, 8);
        lsum[r] = s;
    }

#pragma unroll
    for (int r = 0; r < 4; ++r) {
        int sI = q0 + quad * 4 + r;
        float inv = 1.0f / lsum[r];
        int base = (b * 1024 + sI) * 1024 + h * 64;
#pragma unroll
        for (int j = 0; j < 4; ++j)
            ctx[base + j * 16 + l16] = f2bf(O[j][r] * inv);
    }
}

// ---------------- output projection + residual + fused LN partial sums ----------------
// M=8192, N=1024, K=1024. grid (64, 8), block 256. res = ctx @ wo + x (fp32).
__global__ __launch_bounds__(256) void oproj_gemm_kernel(const u16* __restrict__ ctxb, const u16* __restrict__ wot,
                                                         const float* __restrict__ x, float* __restrict__ res,
                                                         float* __restrict__ sums) {
    __shared__ __align__(16) u16 As[128 * 64];
    __shared__ __align__(16) u16 Bs[128 * 64];

    int t = threadIdx.x;
    int lane = t & 63, w = t >> 6;
    int wm = w & 1, wn = w >> 1;
    int l16 = lane & 15, quad = lane >> 4;
    int sw = l16 & 7;

    int m0 = blockIdx.x * 128;
    int n0 = blockIdx.y * 128;

    int srow = t >> 3;
    int skp = ((t & 7) ^ (srow & 7)) * 8;
    const u16* ga0 = ctxb + (m0 + srow) * 1024 + skp;
    const u16* gb0 = wot + (n0 + srow) * 1024 + skp;

    int arow0 = wm * 64 + l16;
    int brow0 = wn * 64 + l16;

    f32x4 acc[4][4];
#pragma unroll
    for (int i = 0; i < 4; ++i)
#pragma unroll
        for (int j = 0; j < 4; ++j) acc[i][j] = (f32x4){0.f, 0.f, 0.f, 0.f};

    for (int kb0 = 0; kb0 < 1024; kb0 += 64) {
        __syncthreads();
#pragma unroll
        for (int c = 0; c < 4; ++c)
            load_lds16(ga0 + c * 32768 + kb0, &As[c * 2048 + t * 8]);
#pragma unroll
        for (int c = 0; c < 4; ++c)
            load_lds16(gb0 + c * 32768 + kb0, &Bs[c * 2048 + t * 8]);
        __syncthreads();

#pragma unroll
        for (int kh = 0; kh < 2; ++kh) {
            int kidx = ((kh << 2) + quad) ^ sw;
            bf16x8 af[4], bfr[4];
#pragma unroll
            for (int i = 0; i < 4; ++i)
                af[i] = *(const bf16x8*)&As[(arow0 + i * 16) * 64 + kidx * 8];
#pragma unroll
            for (int j = 0; j < 4; ++j)
                bfr[j] = *(const bf16x8*)&Bs[(brow0 + j * 16) * 64 + kidx * 8];
#pragma unroll
            for (int i = 0; i < 4; ++i)
#pragma unroll
                for (int j = 0; j < 4; ++j)
                    acc[i][j] = mfma16(af[i], bfr[j], acc[i][j]);
        }
    }

    float ps = 0.f, ps2 = 0.f;
#pragma unroll
    for (int i = 0; i < 4; ++i) {
#pragma unroll
        for (int r = 0; r < 4; ++r) {
            int m = m0 + wm * 64 + i * 16 + quad * 4 + r;
#pragma unroll
            for (int j = 0; j < 4; ++j) {
                int n = n0 + wn * 64 + j * 16 + l16;
                float v = acc[i][j][r] + x[m * 1024 + n];
                res[m * 1024 + n] = v;
                ps += v; ps2 += v * v;
            }
        }
    }

#pragma unroll
    for (int off = 32; off > 0; off >>= 1) {
        ps += __shfl_xor(ps, off);
        ps2 += __shfl_xor(ps2, off);
    }
    __shared__ float ls[4], ls2[4];
    if (lane == 0) { ls[w] = ps; ls2[w] = ps2; }
    __syncthreads();
    if (t == 0) {
        int b = blockIdx.x >> 3;
        atomicAdd(&sums[b * 2 + 0], ls[0] + ls[1] + ls[2] + ls[3]);
        atomicAdd(&sums[b * 2 + 1], ls2[0] + ls2[1] + ls2[2] + ls2[3]);
    }
}

// ---------------- layernorm normalize (float4-vectorized) ----------------
__global__ __launch_bounds__(256) void norm_kernel(const float* __restrict__ res, const float* __restrict__ sums,
                                                   float* __restrict__ out) {
    int i = (blockIdx.x * 256 + threadIdx.x) * 4;  // grid 8192 -> 8388608
    int b = i >> 20;
    float mean = sums[b * 2 + 0] * (1.0f / 1048576.0f);
    float var = sums[b * 2 + 1] * (1.0f / 1048576.0f) - mean * mean;
    float rs = rsqrtf(var + 1e-5f);
    float4 v = *(const float4*)(res + i);
    float4 o;
    o.x = (v.x - mean) * rs;
    o.y = (v.y - mean) * rs;
    o.z = (v.z - mean) * rs;
    o.w = (v.w - mean) * rs;
    *(float4*)(out + i) = o;
}

// ---------------- launch ----------------

extern "C" void kernel_launch(void* const* d_in, const int* in_sizes, int n_in,
                              void* d_out, int out_size, void* d_ws, size_t ws_size,
                              hipStream_t stream) {
    const int* mask  = (const int*)d_in[0];
    const float* x   = (const float*)d_in[1];
    const float* wq  = (const float*)d_in[2];
    const float* wk  = (const float*)d_in[3];
    const float* wv  = (const float*)d_in[4];
    const float* wo  = (const float*)d_in[5];
    float* out = (float*)d_out;

    char* ws = (char*)d_ws;
    u16* xb    = (u16*)(ws + 0);          // 16,777,216 B
    u16* wt    = (u16*)(ws + 16777216);   //  6,291,456 B
    u16* wot   = (u16*)(ws + 23068672);   //  2,097,152 B
    u16* qb    = (u16*)(ws + 25165824);   // 16,777,216 B
    u16* kb    = (u16*)(ws + 41943040);   // 16,777,216 B
    u16* vtb   = (u16*)(ws + 58720256);   // 16,777,216 B
    float* res = (float*)(ws + 25165824); // 32 MB — aliases qb/kb AFTER attn completes (safe)
    float* sums = (float*)(ws + 75497472);// 64 B
    uint2* mbits = (uint2*)(ws + 76546048); // 1,048,576 B
    u16* ctxb  = (u16*)d_out;             // ctx staged in d_out; overwritten by final norm

    prep_kernel<<<57344, 256, 0, stream>>>(x, wq, wk, wv, wo, mask, xb, wt, wot, mbits, sums);
    qkv_gemm_kernel<<<384, 512, 0, stream>>>(xb, wt, qb, kb, vtb);
    attn_kernel<<<dim3(16, 16, 8), 256, 0, stream>>>(qb, kb, vtb, mbits, ctxb);
    oproj_gemm_kernel<<<dim3(64, 8), 256, 0, stream>>>(ctxb, wot, x, res, sums);
    norm_kernel<<<8192, 256, 0, stream>>>(res, sums, out);
}

// Round 3
// 370.065 us; speedup vs baseline: 1.0125x; 1.0125x over previous
//
#include <hip/hip_runtime.h>

typedef unsigned short u16;
typedef __attribute__((ext_vector_type(8))) short bf16x8;
typedef __attribute__((ext_vector_type(4))) float f32x4;

// Problem: B=8, S=1024, D=1024, H=16, DK=64.
// d_in = {mask:int32, x:f32, wq:f32, wk:f32, wv:f32, wo:f32}. Output: float32.
// Compute path: f32 -> bf16, MFMA 16x16x32 bf16, fp32 accumulate.
// NOTE (R9): hipLaunchCooperativeKernel silently failed in this harness — do not use.

static __device__ __forceinline__ u16 f2bf(float f) {
    union { float f; unsigned u; } v; v.f = f;
    unsigned r = v.u + 0x7fffu + ((v.u >> 16) & 1u);
    return (u16)(r >> 16);
}

static __device__ __forceinline__ f32x4 mfma16(bf16x8 a, bf16x8 b, f32x4 c) {
    return __builtin_amdgcn_mfma_f32_16x16x32_bf16(a, b, c, 0, 0, 0);
}

// async global->LDS, 16 bytes per lane (global_load_lds_dwordx4)
static __device__ __forceinline__ void load_lds16(const u16* g, u16* l) {
    __builtin_amdgcn_global_load_lds((const __attribute__((address_space(1))) unsigned*)(const void*)g,
                                     (__attribute__((address_space(3))) unsigned*)(void*)l, 16, 0, 0);
}

// ---------------- fused prep: cvt_x | cvt_w | pack_mask | zero sums ----------------
// grid 57344: [0,8192) cvt_x, [8192,24576) cvt_w, [24576,57344) pack_mask
__global__ __launch_bounds__(256) void prep_kernel(const float* __restrict__ x,
                                                   const float* __restrict__ wq, const float* __restrict__ wk,
                                                   const float* __restrict__ wv, const float* __restrict__ wo,
                                                   const int* __restrict__ mask,
                                                   u16* __restrict__ xb, u16* __restrict__ wt,
                                                   u16* __restrict__ wot, uint2* __restrict__ mb,
                                                   float* __restrict__ sums) {
    int bid = blockIdx.x;
    if (bid == 0 && threadIdx.x < 16) sums[threadIdx.x] = 0.f;  // zero LN accumulators
    if (bid < 8192) {
        int i = (bid * 256 + threadIdx.x) * 4;  // 8388608 elems
        float4 v = *(const float4*)(x + i);
        ushort4 o;
        o.x = f2bf(v.x); o.y = f2bf(v.y); o.z = f2bf(v.z); o.w = f2bf(v.w);
        *(ushort4*)(xb + i) = o;
    } else if (bid < 24576) {
        int o = (bid - 8192) * 256 + threadIdx.x;  // 4194304 elems
        if (o < 3145728) {
            int z = o >> 20;
            int rem = o & 1048575;
            int n = rem >> 10;
            int d = rem & 1023;
            int h = n >> 6, kk = n & 63;
            const float* w = (z == 0) ? wq : (z == 1) ? wk : wv;
            wt[o] = f2bf(w[h * 65536 + d * 64 + kk]);
        } else {
            int oo = o - 3145728;
            int n = oo >> 10, d = oo & 1023;
            wot[oo] = f2bf(wo[d * 1024 + n]);
        }
    } else {
        long long wi = (long long)(bid - 24576) * 4 + (threadIdx.x >> 6);  // 131072 words
        int lane = threadIdx.x & 63;
        int v = mask[wi * 64 + lane];
        unsigned long long bal = __ballot(v != 0);
        if (lane == 0) {
            uint2 o; o.x = (unsigned)bal; o.y = (unsigned)(bal >> 32);
            mb[wi] = o;
        }
    }
}

// ---------------- fused QKV projection GEMM: 256x256 tile, 8-phase deep pipeline ----------------
// M=8192, N=3072, K=1024. grid 384 (32 m-tiles x 12 n-tiles, XCD-swizzled), block 512 (8 waves, 2Mx4N).
//
// R1 post-mortem: K-split staging (64B/row) doubled FETCH_SIZE (49->103 MB) and starved the pipe.
// R2/R3: ROW-split half-slots (m201 geometry). LDS (128 KiB) = 8 slots x 16 KiB; slot = [128 rows][64 k]
// bf16 with the proven XOR granule swizzle (phys granule = logical_granule ^ (row&7)); 128B/row
// staging (same pattern as the 0-conflict round-0 kernel). Slots: A[par][h] (h=row-half), B[par][h];
// wave wm reads A[par][wm], wave wn reads B[par][wn>>1].
//
// Iteration i computes a=2i (p1-p4: (kh,niH) = 00,01,10,11) and b=2i+1 (p5-p8). Slot lifetimes:
// A[par_a] read p1,p3 (free after p3); B[par_a] read p1-p4; A[par_b] read p5,p7; B[par_b] p5-p8.
// Staging stream (>=2-phase lead into each vmcnt wait; slot-WAR safe, issue >=1 barrier after last read):
//   p1: A(b,1)+B(b,0)   p2: B(b,1)   p3: -   p4: A(c,0) +vmcnt(2)
//   p5: A(c,1)+B(c,0)   p6: B(c,1)   p7: -   p8: A(d,0) +vmcnt(2)      (c=2i+2, d=2i+3)
// vmcnt(2) at p4 leaves only p4's 2 loads in flight => prev-p8/p1/p2 stages landed before p5 reads.
// vmcnt(2) at p8 leaves only p8's => p4/p5/p6 landed before next-p1 reads. Never vmcnt(0) in loop.
// Q pre-scaled by 1/sqrt(DK)=0.125 in the epilogue.
__global__ __launch_bounds__(512, 2) void qkv_gemm_kernel(const u16* __restrict__ xb, const u16* __restrict__ wt,
                                                          u16* __restrict__ qb, u16* __restrict__ kb,
                                                          u16* __restrict__ vtb) {
    __shared__ __align__(16) u16 L[8 * 8192];

    int t = threadIdx.x;
    int lane = t & 63, w = t >> 6;
    int wm = w & 1, wn = w >> 1;         // 2 M-waves x 4 N-waves; wave tile 128x64
    int l16 = lane & 15, quad = lane >> 4;
    int sw8 = l16 & 7;
    int bh = wn >> 1;                    // B row-half for this wave
    int brow = (wn & 1) * 64 + l16;      // B row base within slot

    // XCD-bijective block swizzle (384 % 8 == 0): consecutive ids within an XCD walk m fast.
    int id = blockIdx.x;
    int swz = (id & 7) * 48 + (id >> 3);
    int m0 = (swz & 31) * 256;
    int n0 = (swz >> 5) * 256;

    // Staging: thread t covers row (t>>3) of a 64-row group (two calls -> 128 rows), 128B per row,
    // XOR-permuted within the row: granule (t&7) holds logical granule (t&7)^((t>>3)&7).
    int skp = ((t & 7) ^ ((t >> 3) & 7)) * 8;
    const u16* gA = xb + (m0 + (t >> 3)) * 1024 + skp;
    const u16* gB = wt + (n0 + (t >> 3)) * 1024 + skp;

    f32x4 acc[8][4];
#pragma unroll
    for (int i = 0; i < 8; ++i)
#pragma unroll
        for (int j = 0; j < 4; ++j) acc[i][j] = (f32x4){0.f, 0.f, 0.f, 0.f};
    bf16x8 af[8];

    // A slot (kt,h) at L[((kt&1)*2+h)*8192]; B slot at L[32768 + ((kt&1)*2+h)*8192]
#define STAGE_A(kt, h) { const u16* sgp_ = gA + (h) * 131072 + (kt) * 64;        \
        u16* sdp_ = &L[(((kt) & 1) * 2 + (h)) * 8192];                           \
        load_lds16(sgp_, sdp_ + t * 8);                                          \
        load_lds16(sgp_ + 65536, sdp_ + 4096 + t * 8); }
#define STAGE_B(kt, h) { const u16* sgp_ = gB + (h) * 131072 + (kt) * 64;        \
        u16* sdp_ = &L[32768 + (((kt) & 1) * 2 + (h)) * 8192];                   \
        load_lds16(sgp_, sdp_ + t * 8);                                          \
        load_lds16(sgp_ + 65536, sdp_ + 4096 + t * 8); }
#define VM2 asm volatile("s_waitcnt vmcnt(2)" ::: "memory");
#define VM0 asm volatile("s_waitcnt vmcnt(0)" ::: "memory");

#define PHASE(par, kh, niH, STG, WT) {                                           \
        const u16* SA_ = &L[((par) * 2 + wm) * 8192];                            \
        const u16* SB_ = &L[32768 + ((par) * 2 + bh) * 8192];                    \
        int gix_ = ((((kh) << 2) + quad) ^ sw8) * 8;                             \
        if ((niH) == 0) {                                                        \
            _Pragma("unroll")                                                    \
            for (int mi = 0; mi < 8; ++mi)                                       \
                af[mi] = *(const bf16x8*)&SA_[(mi * 16 + l16) * 64 + gix_];      \
        }                                                                        \
        bf16x8 b0_ = *(const bf16x8*)&SB_[(brow + ((niH) * 2 + 0) * 16) * 64 + gix_]; \
        bf16x8 b1_ = *(const bf16x8*)&SB_[(brow + ((niH) * 2 + 1) * 16) * 64 + gix_]; \
        STG                                                                      \
        __builtin_amdgcn_s_barrier();                                            \
        asm volatile("s_waitcnt lgkmcnt(0)" ::: "memory");                       \
        __builtin_amdgcn_sched_barrier(0);                                       \
        __builtin_amdgcn_s_setprio(1);                                           \
        _Pragma("unroll")                                                        \
        for (int mi = 0; mi < 8; ++mi) {                                         \
            acc[mi][(niH) * 2 + 0] = mfma16(af[mi], b0_, acc[mi][(niH) * 2 + 0]);\
            acc[mi][(niH) * 2 + 1] = mfma16(af[mi], b1_, acc[mi][(niH) * 2 + 1]);\
        }                                                                        \
        __builtin_amdgcn_s_setprio(0);                                           \
        WT                                                                       \
        __builtin_amdgcn_s_barrier(); }

    // prologue: kt0 fully + A(1,0); drain kt0's 8 loads, leave A(1,0)'s 2 in flight
    STAGE_A(0, 0) STAGE_A(0, 1) STAGE_B(0, 0) STAGE_B(0, 1) STAGE_A(1, 0)
    VM2
    __builtin_amdgcn_s_barrier();

    for (int i = 0; i < 7; ++i) {
        int kb1 = 2 * i + 1, kc2 = 2 * i + 2, kd3 = 2 * i + 3;
        PHASE(0, 0, 0, STAGE_A(kb1, 1) STAGE_B(kb1, 0), )   // p1
        PHASE(0, 0, 1, STAGE_B(kb1, 1), )                   // p2
        PHASE(0, 1, 0, , )                                  // p3
        PHASE(0, 1, 1, STAGE_A(kc2, 0), VM2)                // p4
        PHASE(1, 0, 0, STAGE_A(kc2, 1) STAGE_B(kc2, 0), )   // p5
        PHASE(1, 0, 1, STAGE_B(kc2, 1), )                   // p6
        PHASE(1, 1, 0, , )                                  // p7
        PHASE(1, 1, 1, STAGE_A(kd3, 0), VM2)                // p8
    }
    // tail: a=14 (par0), b=15 (par1). A(15,0) staged at i=6 p8.
    PHASE(0, 0, 0, STAGE_A(15, 1) STAGE_B(15, 0), )
    PHASE(0, 0, 1, STAGE_B(15, 1), )
    PHASE(0, 1, 0, , )
    PHASE(0, 1, 1, , VM0)
    PHASE(1, 0, 0, , )
    PHASE(1, 0, 1, , )
    PHASE(1, 1, 0, , )
    PHASE(1, 1, 1, , )

#undef PHASE
#undef STAGE_A
#undef STAGE_B
#undef VM2
#undef VM0

    // epilogue: scatter to per-head Q/K/V layouts (z uniform per block since 256 | 1024)
    int z = n0 >> 10;
    float qscale = (z == 0) ? 0.125f : 1.0f;
#pragma unroll
    for (int mi = 0; mi < 8; ++mi) {
#pragma unroll
        for (int r = 0; r < 4; ++r) {
            int m = m0 + wm * 128 + mi * 16 + quad * 4 + r;
            int b_ = m >> 10, s = m & 1023;
#pragma unroll
            for (int ni = 0; ni < 4; ++ni) {
                int ng = n0 + wn * 64 + ni * 16 + l16;
                int nl = ng & 1023;
                int h = nl >> 6, kk = nl & 63;
                u16 val = f2bf(acc[mi][ni][r] * qscale);
                if (z == 0)      qb[((b_ * 16 + h) * 1024 + s) * 64 + kk] = val;
                else if (z == 1) kb[((b_ * 16 + h) * 1024 + s) * 64 + kk] = val;
                else             vtb[((b_ * 16 + h) * 64 + kk) * 1024 + s] = val;
            }
        }
    }
}

// ---------------- flash attention: LDS-staged K/V + bitmask ----------------
// grid (S/64, H, B), block 256 = 4 waves; wave: 16 queries, 64-key tiles.
__global__ __launch_bounds__(256) void attn_kernel(const u16* __restrict__ qb, const u16* __restrict__ kb,
                                                   const u16* __restrict__ vtb, const uint2* __restrict__ mb,
                                                   u16* __restrict__ ctx) {
    __shared__ __align__(16) u16 Ks[64 * 64];
    __shared__ __align__(16) u16 Vs[64 * 64];
    __shared__ __align__(16) u16 P[4][16][72];  // rows padded: 36 dw stride -> <=2-way (free)

    int t = threadIdx.x;
    int w = t >> 6, lane = t & 63;
    int l16 = lane & 15, quad = lane >> 4;
    int h = blockIdx.y, b = blockIdx.z;
    int q0 = blockIdx.x * 64 + w * 16;

    const u16* Q = qb + (b * 16 + h) * 65536;
    const u16* K = kb + (b * 16 + h) * 65536;
    const u16* Vt = vtb + (b * 16 + h) * 65536;
    const uint2* MB = mb + (b * 1024 + q0) * 16;

    int srow = t >> 3;
    int skp = ((t & 7) ^ (srow & 7)) * 8;
    const u16* gk0 = K + srow * 64 + skp;          // + (k0+c*32)*64
    const u16* gv0 = Vt + srow * 1024 + skp;       // + c*32*1024 + k0

    bf16x8 qf0 = *(const bf16x8*)(Q + (q0 + l16) * 64 + quad * 8);
    bf16x8 qf1 = *(const bf16x8*)(Q + (q0 + l16) * 64 + 32 + quad * 8);

    f32x4 O[4];
#pragma unroll
    for (int j = 0; j < 4; ++j) O[j] = (f32x4){0.f, 0.f, 0.f, 0.f};
    float lsum[4] = {0.f, 0.f, 0.f, 0.f};

    int sw = l16 & 7;

    for (int kt0 = 0; kt0 < 16; ++kt0) {
        int k0 = kt0 * 64;

        // hoist mask-word loads: issue before the barriers, consume after staging
        uint2 mw[4];
#pragma unroll
        for (int r = 0; r < 4; ++r)
            mw[r] = MB[(quad * 4 + r) * 16 + kt0];

        __syncthreads();
#pragma unroll
        for (int c = 0; c < 2; ++c) {
            load_lds16(gk0 + (k0 + c * 32) * 64, &Ks[c * 2048 + t * 8]);
            load_lds16(gv0 + c * 32 * 1024 + k0, &Vs[c * 2048 + t * 8]);
        }
        __syncthreads();

        f32x4 s[4];
#pragma unroll
        for (int kt = 0; kt < 4; ++kt) {
            int row = kt * 16 + l16;
            bf16x8 klo = *(const bf16x8*)&Ks[row * 64 + ((quad ^ sw) * 8)];
            bf16x8 khi = *(const bf16x8*)&Ks[row * 64 + (((4 + quad) ^ sw) * 8)];
            f32x4 z = {0.f, 0.f, 0.f, 0.f};
            z = mfma16(qf0, klo, z);
            z = mfma16(qf1, khi, z);
            s[kt] = z;
        }

#pragma unroll
        for (int r = 0; r < 4; ++r) {
            int qrow = quad * 4 + r;
#pragma unroll
            for (int kt = 0; kt < 4; ++kt) {
                unsigned wsel = (kt < 2) ? mw[r].x : mw[r].y;
                unsigned bit = (wsel >> ((kt & 1) * 16 + l16)) & 1u;
                float e = bit ? __expf(s[kt][r]) : 0.f;
                lsum[r] += e;
                P[w][qrow][kt * 16 + l16] = f2bf(e);
            }
        }

        // P: C-layout -> A-layout via same-wave LDS round trip (in-order DS pipe, no barrier)
        bf16x8 pf0 = *(const bf16x8*)&P[w][l16][quad * 8];
        bf16x8 pf1 = *(const bf16x8*)&P[w][l16][32 + quad * 8];

#pragma unroll
        for (int j = 0; j < 4; ++j) {
            int row = j * 16 + l16;
            bf16x8 vlo = *(const bf16x8*)&Vs[row * 64 + ((quad ^ sw) * 8)];
            bf16x8 vhi = *(const bf16x8*)&Vs[row * 64 + (((4 + quad) ^ sw) * 8)];
            O[j] = mfma16(pf0, vlo, O[j]);
            O[j] = mfma16(pf1, vhi, O[j]);
        }
    }

#pragma unroll
    for (int r = 0; r < 4; ++r) {
        float s = lsum[r];
        s += __shfl_xor(s, 1);
        s += __shfl_xor(s, 2);
        s += __shfl_xor(s, 4);
        s += __shfl_xor(s, 8);
        lsum[r] = s;
    }

#pragma unroll
    for (int r = 0; r < 4; ++r) {
        int sI = q0 + quad * 4 + r;
        float inv = 1.0f / lsum[r];
        int base = (b * 1024 + sI) * 1024 + h * 64;
#pragma unroll
        for (int j = 0; j < 4; ++j)
            ctx[base + j * 16 + l16] = f2bf(O[j][r] * inv);
    }
}

// ---------------- output projection + residual + fused LN partial sums ----------------
// M=8192, N=1024, K=1024. grid (64, 8), block 256. res = ctx @ wo + x (fp32).
__global__ __launch_bounds__(256) void oproj_gemm_kernel(const u16* __restrict__ ctxb, const u16* __restrict__ wot,
                                                         const float* __restrict__ x, float* __restrict__ res,
                                                         float* __restrict__ sums) {
    __shared__ __align__(16) u16 As[128 * 64];
    __shared__ __align__(16) u16 Bs[128 * 64];

    int t = threadIdx.x;
    int lane = t & 63, w = t >> 6;
    int wm = w & 1, wn = w >> 1;
    int l16 = lane & 15, quad = lane >> 4;
    int sw = l16 & 7;

    int m0 = blockIdx.x * 128;
    int n0 = blockIdx.y * 128;

    int srow = t >> 3;
    int skp = ((t & 7) ^ (srow & 7)) * 8;
    const u16* ga0 = ctxb + (m0 + srow) * 1024 + skp;
    const u16* gb0 = wot + (n0 + srow) * 1024 + skp;

    int arow0 = wm * 64 + l16;
    int brow0 = wn * 64 + l16;

    f32x4 acc[4][4];
#pragma unroll
    for (int i = 0; i < 4; ++i)
#pragma unroll
        for (int j = 0; j < 4; ++j) acc[i][j] = (f32x4){0.f, 0.f, 0.f, 0.f};

    for (int kb0 = 0; kb0 < 1024; kb0 += 64) {
        __syncthreads();
#pragma unroll
        for (int c = 0; c < 4; ++c)
            load_lds16(ga0 + c * 32768 + kb0, &As[c * 2048 + t * 8]);
#pragma unroll
        for (int c = 0; c < 4; ++c)
            load_lds16(gb0 + c * 32768 + kb0, &Bs[c * 2048 + t * 8]);
        __syncthreads();

#pragma unroll
        for (int kh = 0; kh < 2; ++kh) {
            int kidx = ((kh << 2) + quad) ^ sw;
            bf16x8 af[4], bfr[4];
#pragma unroll
            for (int i = 0; i < 4; ++i)
                af[i] = *(const bf16x8*)&As[(arow0 + i * 16) * 64 + kidx * 8];
#pragma unroll
            for (int j = 0; j < 4; ++j)
                bfr[j] = *(const bf16x8*)&Bs[(brow0 + j * 16) * 64 + kidx * 8];
#pragma unroll
            for (int i = 0; i < 4; ++i)
#pragma unroll
                for (int j = 0; j < 4; ++j)
                    acc[i][j] = mfma16(af[i], bfr[j], acc[i][j]);
        }
    }

    float ps = 0.f, ps2 = 0.f;
#pragma unroll
    for (int i = 0; i < 4; ++i) {
#pragma unroll
        for (int r = 0; r < 4; ++r) {
            int m = m0 + wm * 64 + i * 16 + quad * 4 + r;
#pragma unroll
            for (int j = 0; j < 4; ++j) {
                int n = n0 + wn * 64 + j * 16 + l16;
                float v = acc[i][j][r] + x[m * 1024 + n];
                res[m * 1024 + n] = v;
                ps += v; ps2 += v * v;
            }
        }
    }

#pragma unroll
    for (int off = 32; off > 0; off >>= 1) {
        ps += __shfl_xor(ps, off);
        ps2 += __shfl_xor(ps2, off);
    }
    __shared__ float ls[4], ls2[4];
    if (lane == 0) { ls[w] = ps; ls2[w] = ps2; }
    __syncthreads();
    if (t == 0) {
        int b = blockIdx.x >> 3;
        atomicAdd(&sums[b * 2 + 0], ls[0] + ls[1] + ls[2] + ls[3]);
        atomicAdd(&sums[b * 2 + 1], ls2[0] + ls2[1] + ls2[2] + ls2[3]);
    }
}

// ---------------- layernorm normalize (float4-vectorized) ----------------
__global__ __launch_bounds__(256) void norm_kernel(const float* __restrict__ res, const float* __restrict__ sums,
                                                   float* __restrict__ out) {
    int i = (blockIdx.x * 256 + threadIdx.x) * 4;  // grid 8192 -> 8388608
    int b = i >> 20;
    float mean = sums[b * 2 + 0] * (1.0f / 1048576.0f);
    float var = sums[b * 2 + 1] * (1.0f / 1048576.0f) - mean * mean;
    float rs = rsqrtf(var + 1e-5f);
    float4 v = *(const float4*)(res + i);
    float4 o;
    o.x = (v.x - mean) * rs;
    o.y = (v.y - mean) * rs;
    o.z = (v.z - mean) * rs;
    o.w = (v.w - mean) * rs;
    *(float4*)(out + i) = o;
}

// ---------------- launch ----------------

extern "C" void kernel_launch(void* const* d_in, const int* in_sizes, int n_in,
                              void* d_out, int out_size, void* d_ws, size_t ws_size,
                              hipStream_t stream) {
    const int* mask  = (const int*)d_in[0];
    const float* x   = (const float*)d_in[1];
    const float* wq  = (const float*)d_in[2];
    const float* wk  = (const float*)d_in[3];
    const float* wv  = (const float*)d_in[4];
    const float* wo  = (const float*)d_in[5];
    float* out = (float*)d_out;

    char* ws = (char*)d_ws;
    u16* xb    = (u16*)(ws + 0);          // 16,777,216 B
    u16* wt    = (u16*)(ws + 16777216);   //  6,291,456 B
    u16* wot   = (u16*)(ws + 23068672);   //  2,097,152 B
    u16* qb    = (u16*)(ws + 25165824);   // 16,777,216 B
    u16* kb    = (u16*)(ws + 41943040);   // 16,777,216 B
    u16* vtb   = (u16*)(ws + 58720256);   // 16,777,216 B
    float* res = (float*)(ws + 25165824); // 32 MB — aliases qb/kb AFTER attn completes (safe)
    float* sums = (float*)(ws + 75497472);// 64 B
    uint2* mbits = (uint2*)(ws + 76546048); // 1,048,576 B
    u16* ctxb  = (u16*)d_out;             // ctx staged in d_out; overwritten by final norm

    prep_kernel<<<57344, 256, 0, stream>>>(x, wq, wk, wv, wo, mask, xb, wt, wot, mbits, sums);
    qkv_gemm_kernel<<<384, 512, 0, stream>>>(xb, wt, qb, kb, vtb);
    attn_kernel<<<dim3(16, 16, 8), 256, 0, stream>>>(qb, kb, vtb, mbits, ctxb);
    oproj_gemm_kernel<<<dim3(64, 8), 256, 0, stream>>>(ctxb, wot, x, res, sums);
    norm_kernel<<<8192, 256, 0, stream>>>(res, sums, out);
}